// Round 16
// baseline (460.884 us; speedup 1.0000x reference)
//
#include <hip/hip_runtime.h>
#include <cstdint>
#include <cstddef>

#define S_LEN 2048
#define DM    4096
#define NH    32
#define NKV   8
#define HDIM  128
#define EQ    4096   // NH*HDIM
#define EKV   1024   // NKV*HDIM
#define SC_LOG2E 0.1275325477889277f   // (1/sqrt(128)) * log2(e)

typedef unsigned short u16;
typedef short bf16x8 __attribute__((ext_vector_type(8)));
typedef float f32x4  __attribute__((ext_vector_type(4)));

__device__ __forceinline__ u16 f2bf(float f) {
  union { float f; unsigned u; } v; v.f = f;
  unsigned r = v.u + 0x7FFFu + ((v.u >> 16) & 1u);
  return (u16)(r >> 16);
}
__device__ __forceinline__ float bf2f(u16 b) {
  union { unsigned u; float f; } v; v.u = ((unsigned)b) << 16;
  return v.f;
}
// HW packed fp32->bf16 RNE (ties-even, same as f2bf); a -> low 16, b -> high 16
__device__ __forceinline__ unsigned cvt2bf(float a, float b) {
  unsigned r;
  asm("v_cvt_pk_bf16_f32 %0, %1, %2" : "=v"(r) : "v"(a), "v"(b));
  return r;
}
__device__ __forceinline__ void glds16(const void* g, void* l) {
  __builtin_amdgcn_global_load_lds((const __attribute__((address_space(1))) void*)g,
                                   (__attribute__((address_space(3))) void*)l, 16, 0, 0);
}

// ---------------------------------------------------------------- cast fp32->bf16
__global__ void cast_all(const float* __restrict__ x, const float* __restrict__ wq,
                         const float* __restrict__ wk, const float* __restrict__ wv,
                         const float* __restrict__ wo,
                         u16* __restrict__ xb, u16* __restrict__ wqb,
                         u16* __restrict__ wkb, u16* __restrict__ wvb,
                         u16* __restrict__ wob) {
  const size_t stride = (size_t)gridDim.x * blockDim.x;
  for (size_t u = (size_t)blockIdx.x * blockDim.x + threadIdx.x; u < 12582912u; u += stride) {
    const float* in; u16* outp; size_t i;
    if (u < 2097152u)      { in = x;  outp = xb;  i = u; }
    else if (u < 6291456u) { in = wq; outp = wqb; i = u - 2097152u; }
    else if (u < 7340032u) { in = wk; outp = wkb; i = u - 6291456u; }
    else if (u < 8388608u) { in = wv; outp = wvb; i = u - 7340032u; }
    else                   { in = wo; outp = wob; i = u - 8388608u; }
    float4 f = ((const float4*)in)[i];
    ushort4 b;
    b.x = f2bf(f.x); b.y = f2bf(f.y); b.z = f2bf(f.z); b.w = f2bf(f.w);
    ((ushort4*)outp)[i] = b;
  }
}

// ---------------------------------------------------------------- single-buffer GEMM, 4 blocks/CU
// C = A * B^T, bf16 row-major. BM=128, BN=64*NF, BK=64, 4 waves (2x2).
// NEW vs R15: NO double-buffer — LDS = 40 KB (NF=3) / 32 KB (NF=2) ->
// 4 blocks/CU = 16 waves/CU = 4 waves/SIMD. Each block's stage drain
// (barrier; stage; barrier) is covered by the 3 other blocks' MFMA phases
// (m114 co-schedule) instead of intra-block prefetch. Inner loop, swizzle
// (u ^= row&7 both-sides), epilogue, XCD map: identical to the proven R15.
template<int UN>
__device__ __forceinline__ void stage_t(const u16* __restrict__ g, int ldg, int k0,
                                        u16* ldsp, int t) {
  const int wb = t & ~63;
#pragma unroll
  for (int j = 0; j < UN / 256; ++j) {
    const int U = j * 256 + t;
    const int row = U >> 3, u = U & 7;
    const int uu = u ^ (row & 7);
    glds16(g + (size_t)row * ldg + k0 + uu * 8, ldsp + (size_t)(j * 256 + wb) * 8);
  }
}

template<int NF, bool QKV3>
__global__ __launch_bounds__(256, 4)
void gemm2p(const u16* __restrict__ A, const u16* __restrict__ B,
            void* __restrict__ Cq, u16* __restrict__ Ck, u16* __restrict__ Cv,
            int K) {
  constexpr int BN = 64 * NF;
  constexpr int AT = 128 * 64;        // u16 per A tile (8192)
  constexpr int BT = BN * 64;         // u16 per B tile
  __shared__ u16 lds[AT + BT];        // single buffer: A @0, B @AT
  const int t = threadIdx.x;
  const int l = t & 63, lr = l & 15, lg = l >> 4;
  const int wid = t >> 6, wm = wid >> 1, wn = wid & 1;

  const int bid = blockIdx.x;
  const int xcd = bid & 7, j = bid >> 3;
  const int bx = xcd * 4 + (j >> 4);
  const int by = j & 15;
  const int m0 = by * 128, n0 = bx * BN;
  const int KT = K >> 6;

  const u16* Ab = A + (size_t)m0 * K;
  const u16* Bb = B + (size_t)n0 * K;

  f32x4 acc[4][2 * NF] = {};

#pragma unroll 1
  for (int tau = 0; tau < KT; ++tau) {
    __syncthreads();                  // all waves done reading previous tile
    stage_t<1024>(Ab, K, tau * 64, &lds[0], t);
    stage_t<BT / 8>(Bb, K, tau * 64, &lds[AT], t);
    __syncthreads();                  // stage drained (vmcnt(0) implicit)

    bf16x8 af[4][2];
#pragma unroll
    for (int mf = 0; mf < 4; ++mf)
#pragma unroll
      for (int kk = 0; kk < 2; ++kk) {
        const int row = wm * 64 + mf * 16 + lr;
        const int uu = ((kk * 4 + lg) ^ (row & 7)) * 8;
        af[mf][kk] = *(const bf16x8*)&lds[row * 64 + uu];
      }

#pragma unroll
    for (int n = 0; n < 2 * NF; ++n) {
      const int brow = wn * (32 * NF) + n * 16 + lr;
      const int u0 = ((0 * 4 + lg) ^ (brow & 7)) * 8;
      const int u1 = ((1 * 4 + lg) ^ (brow & 7)) * 8;
      bf16x8 b0 = *(const bf16x8*)&lds[AT + brow * 64 + u0];
      bf16x8 b1 = *(const bf16x8*)&lds[AT + brow * 64 + u1];
#pragma unroll
      for (int mf = 0; mf < 4; ++mf) {
        acc[mf][n] = __builtin_amdgcn_mfma_f32_16x16x32_bf16(af[mf][0], b0, acc[mf][n], 0, 0, 0);
        acc[mf][n] = __builtin_amdgcn_mfma_f32_16x16x32_bf16(af[mf][1], b1, acc[mf][n], 0, 0, 0);
      }
    }
  }

  // epilogue; fragment cols are 16-aligned so QKV routing is per-fragment
#pragma unroll
  for (int mf = 0; mf < 4; ++mf) {
    const int row = m0 + wm * 64 + mf * 16 + lg * 4;
#pragma unroll
    for (int n = 0; n < 2 * NF; ++n) {
      const int gc = n0 + wn * (32 * NF) + n * 16 + lr;
#pragma unroll
      for (int r = 0; r < 4; ++r) {
        if constexpr (QKV3) {
          if (gc < 4096)
            ((u16*)Cq)[(size_t)(row + r) * 4096 + gc] = f2bf(acc[mf][n][r]);
          else if (gc < 5120)
            Ck[(size_t)(row + r) * 1024 + (gc - 4096)] = f2bf(acc[mf][n][r]);
          else
            Cv[(size_t)(row + r) * 1024 + (gc - 5120)] = f2bf(acc[mf][n][r]);
        } else {
          ((float*)Cq)[(size_t)(row + r) * 4096 + gc] = acc[mf][n][r];
        }
      }
    }
  }
}

// ---------------------------------------------------------------- fused RoPE + V-transpose
__global__ void rope_tr(u16* __restrict__ qd, u16* __restrict__ kd,
                        const float* __restrict__ cosb, const float* __restrict__ sinb,
                        const int* __restrict__ sidx,
                        const u16* __restrict__ v, u16* __restrict__ vt) {
  const int bid = blockIdx.x, t = threadIdx.x;
  if (bid < 5120) {
    const int u = bid * 256 + t;
    u16* base; int s, b;
    if (u < 1048576) {
      base = qd + (size_t)u * 8;
      s = u >> 9;
      b = u & 15;
    } else {
      const int u2 = u - 1048576;
      base = kd + (size_t)u2 * 8;
      s = u2 >> 7;
      b = u2 & 15;
    }
    const int pos = sidx[s];
    const float4 c  = *(const float4*)&cosb[pos * 64 + b * 4];
    const float4 sn = *(const float4*)&sinb[pos * 64 + b * 4];
    uint4 raw = *(uint4*)base;
    u16* pe = (u16*)&raw;
    const float cc[4] = {c.x, c.y, c.z, c.w};
    const float ss[4] = {sn.x, sn.y, sn.z, sn.w};
#pragma unroll
    for (int j = 0; j < 4; ++j) {
      const float xr = bf2f(pe[2 * j]), xi = bf2f(pe[2 * j + 1]);
      pe[2 * j]     = f2bf(xr * cc[j] - xi * ss[j]);
      pe[2 * j + 1] = f2bf(xr * ss[j] + xi * cc[j]);
    }
    *(uint4*)base = raw;
  } else {
    __shared__ u16 tile[32][33];
    const int tb = bid - 5120;
    const int c0 = (tb & 31) * 32, s0 = (tb >> 5) * 32;
    const int tx = t & 31, ty = t >> 5;   // 32 x 8
#pragma unroll
    for (int j = 0; j < 32; j += 8)
      tile[ty + j][tx] = v[(size_t)(s0 + ty + j) * EKV + c0 + tx];
    __syncthreads();
#pragma unroll
    for (int j = 0; j < 32; j += 8)
      vt[(size_t)(c0 + ty + j) * S_LEN + s0 + tx] = tile[tx][ty + j];
  }
}

// ---------------------------------------------------------------- flash attention
// (R15 form, measured ~55us: split causal pairing, single-buffered K/V
// 41.6 KB -> 3 blocks/CU, swapped QK^T with in-register softmax.)
#define ATTN_STAGE(TK) { \
  const int kv0s = (TK) * 64; \
  _Pragma("unroll") \
  for (int hh = 0; hh < 4; ++hh) { \
    const int f = hh * 256 + t; \
    { const int row = f >> 4, uu = f & 15, us = uu ^ (row & 7); \
      glds16(&k[(size_t)(kv0s + row) * EKV + kvh * HDIM + us * 8], &lK[(hh * 256 + wb) * 8]); } \
    { const int row = f >> 3, uu = f & 7, us = uu ^ (row & 7); \
      glds16(&vt[(size_t)(kvh * HDIM + row) * S_LEN + kv0s + us * 8], &lV[(hh * 256 + wb) * 8]); } \
  } }

__global__ __launch_bounds__(256, 3)
void attn_fwd(const u16* __restrict__ q, const u16* __restrict__ k,
              const u16* __restrict__ vt, u16* __restrict__ ao) {
  __shared__ u16 lK[64 * 128];
  __shared__ u16 lV[128 * 64];
  __shared__ u16 lP[4 * 16 * 72];
  const int t = threadIdx.x, w = t >> 6, l = t & 63;
  const int lr = l & 15, lg = l >> 4;
  const int wb = t & ~63;
  const int p = blockIdx.x, h = blockIdx.y;
  const int kvh = h >> 2;
  u16* lPw = &lP[w * (16 * 72)];

#pragma unroll 1
  for (int ph = 0; ph < 2; ++ph) {
    const int qt = ph ? (31 - p) : p;
    const int q0 = qt * 64 + w * 16;
    const int nt = qt + 1;

    bf16x8 qa[4];
#pragma unroll
    for (int kc = 0; kc < 4; ++kc)
      qa[kc] = *(const bf16x8*)&q[(size_t)(q0 + lr) * EQ + h * HDIM + kc * 32 + lg * 8];

    f32x4 o[8] = {};
    float mrun = -1e30f, lrun = 0.f;   // per-lane: q = q0 + lr

#pragma unroll 1
    for (int tk = 0; tk < nt; ++tk) {
      const int kv0 = tk * 64;
      __syncthreads();                 // prior compute done reading LDS
      ATTN_STAGE(tk);
      __syncthreads();                 // stage drained (vmcnt(0) implicit)

      // swapped QK^T: sc[n] has q = lr, kv = kv0 + n*16 + lg*4 + r
      f32x4 sc[4] = {};
#pragma unroll
      for (int n = 0; n < 4; ++n) {
#pragma unroll
        for (int kc = 0; kc < 4; ++kc) {
          const int row = n * 16 + lr;
          const int us = (kc * 4 + lg) ^ (row & 7);
          bf16x8 bk = *(const bf16x8*)&lK[row * 128 + us * 8];
          sc[n] = __builtin_amdgcn_mfma_f32_16x16x32_bf16(bk, qa[kc], sc[n], 0, 0, 0);
        }
      }

      // mask + scale (log2 domain)
      const int qr = q0 + lr;
#pragma unroll
      for (int n = 0; n < 4; ++n)
#pragma unroll
        for (int r = 0; r < 4; ++r) {
          const int kvc = kv0 + n * 16 + lg * 4 + r;
          const float vv = sc[n][r] * SC_LOG2E;
          sc[n][r] = (kvc > qr) ? -1e30f : vv;
        }

      // in-register row reduce (row = one q, spread over lanes lr, xor16/32)
      float vmx = sc[0][0];
#pragma unroll
      for (int n = 0; n < 4; ++n)
#pragma unroll
        for (int r = 0; r < 4; ++r) vmx = fmaxf(vmx, sc[n][r]);
      vmx = fmaxf(vmx, __shfl_xor(vmx, 16));
      vmx = fmaxf(vmx, __shfl_xor(vmx, 32));
      const float mn = fmaxf(mrun, vmx);
      const float sf = __builtin_amdgcn_exp2f(mrun - mn);
      mrun = mn;
      float rs = 0.f;
#pragma unroll
      for (int n = 0; n < 4; ++n)
#pragma unroll
        for (int r = 0; r < 4; ++r) {
          const float pv = __builtin_amdgcn_exp2f(sc[n][r] - mn);
          sc[n][r] = pv;
          rs += pv;
        }
      rs += __shfl_xor(rs, 16);
      rs += __shfl_xor(rs, 32);
      lrun = lrun * sf + rs;

      // o rescale: o[nh][r] sits at q = lg*4 + r -> fetch sf from lane lg*4+r
      {
        const float s0 = __shfl(sf, lg * 4 + 0);
        const float s1 = __shfl(sf, lg * 4 + 1);
        const float s2 = __shfl(sf, lg * 4 + 2);
        const float s3 = __shfl(sf, lg * 4 + 3);
#pragma unroll
        for (int nh = 0; nh < 8; ++nh) {
          o[nh][0] *= s0; o[nh][1] *= s1; o[nh][2] *= s2; o[nh][3] *= s3;
        }
      }

      // P -> LDS: lane's 4 kv-contiguous values per n -> cvt_pk + ds_write_b64
#pragma unroll
      for (int n = 0; n < 4; ++n) {
        uint2 wpk;
        wpk.x = cvt2bf(sc[n][0], sc[n][1]);
        wpk.y = cvt2bf(sc[n][2], sc[n][3]);
        *(uint2*)&lPw[lr * 72 + n * 16 + lg * 4] = wpk;
      }

      // PV (unchanged): pa has q = lr rows, kv-contiguous k
#pragma unroll
      for (int kc2 = 0; kc2 < 2; ++kc2) {
        bf16x8 pa = *(const bf16x8*)&lPw[lr * 72 + kc2 * 32 + lg * 8];
#pragma unroll
        for (int nh = 0; nh < 8; ++nh) {
          const int row = nh * 16 + lr;
          const int us = (kc2 * 4 + lg) ^ (row & 7);
          bf16x8 bv = *(const bf16x8*)&lV[row * 64 + us * 8];
          o[nh] = __builtin_amdgcn_mfma_f32_16x16x32_bf16(pa, bv, o[nh], 0, 0, 0);
        }
      }
    }

    // lrun lives at q=lr; outputs need q=lg*4+r
    {
      const float l0 = __shfl(lrun, lg * 4 + 0), l1 = __shfl(lrun, lg * 4 + 1);
      const float l2 = __shfl(lrun, lg * 4 + 2), l3 = __shfl(lrun, lg * 4 + 3);
      const float rl[4] = {l0, l1, l2, l3};
#pragma unroll
      for (int nh = 0; nh < 8; ++nh)
#pragma unroll
        for (int r = 0; r < 4; ++r) {
          const float val = o[nh][r] / rl[r];
          ao[(size_t)(q0 + lg * 4 + r) * EQ + h * HDIM + nh * 16 + lr] = f2bf(val);
        }
    }
  }
}

// ---------------------------------------------------------------- launch
extern "C" void kernel_launch(void* const* d_in, const int* in_sizes, int n_in,
                              void* d_out, int out_size, void* d_ws, size_t ws_size,
                              hipStream_t stream) {
  (void)in_sizes; (void)n_in; (void)out_size; (void)ws_size;
  const float* x    = (const float*)d_in[0];
  const float* wq   = (const float*)d_in[1];
  const float* wk   = (const float*)d_in[2];
  const float* wv   = (const float*)d_in[3];
  const float* wo   = (const float*)d_in[4];
  const float* cosb = (const float*)d_in[7];
  const float* sinb = (const float*)d_in[8];
  const int*   sidx = (const int*)d_in[10];
  float* out = (float*)d_out;

  // workspace layout; wqb/wkb/wvb are contiguous so B_qkv = [wq;wk;wv]
  u16* ws  = (u16*)d_ws;
  u16* xb  = ws;                                  // 2048*4096
  u16* wqb = xb  + (size_t)S_LEN * DM;            // 4096*4096
  u16* wkb = wqb + (size_t)EQ * DM;               // 1024*4096
  u16* wvb = wkb + (size_t)EKV * DM;              // 1024*4096
  u16* wob = wvb + (size_t)EKV * DM;              // 4096*4096
  u16* qb  = wob + (size_t)DM * EQ;               // 2048*4096
  u16* kb  = qb  + (size_t)S_LEN * EQ;            // 2048*1024
  u16* vb  = kb  + (size_t)S_LEN * EKV;           // 2048*1024
  u16* vtb = vb  + (size_t)S_LEN * EKV;           // 1024*2048
  u16* aob = vtb + (size_t)S_LEN * EKV;           // 2048*4096

  cast_all<<<2048, 256, 0, stream>>>(x, wq, wk, wv, wo, xb, wqb, wkb, wvb, wob);
  // fused QKV projection: B = [wq;wk;wv] (6144 x 4096); 1D grid 512, XCD-swizzled
  gemm2p<3, true><<<512, 256, 0, stream>>>(xb, wqb, qb, kb, vb, DM);
  // fused RoPE(q,k) + V-transpose: one dispatch, 5120 + 2048 blocks
  rope_tr<<<7168, 256, 0, stream>>>(qb, kb, cosb, sinb, sidx, vb, vtb);
  attn_fwd<<<dim3(16, NH), 256, 0, stream>>>(qb, kb, vtb, aob);
  // O projection: 1D grid 512, XCD-swizzled
  gemm2p<2, false><<<512, 256, 0, stream>>>(aob, wob, out, nullptr, nullptr, EQ);
}

// Round 17
// 300.397 us; speedup vs baseline: 1.5342x; 1.5342x over previous
//
#include <hip/hip_runtime.h>
#include <cstdint>
#include <cstddef>

#define S_LEN 2048
#define DM    4096
#define NH    32
#define NKV   8
#define HDIM  128
#define EQ    4096   // NH*HDIM
#define EKV   1024   // NKV*HDIM
#define SC_LOG2E 0.1275325477889277f   // (1/sqrt(128)) * log2(e)

typedef unsigned short u16;
typedef short bf16x8 __attribute__((ext_vector_type(8)));
typedef float f32x4  __attribute__((ext_vector_type(4)));

__device__ __forceinline__ u16 f2bf(float f) {
  union { float f; unsigned u; } v; v.f = f;
  unsigned r = v.u + 0x7FFFu + ((v.u >> 16) & 1u);
  return (u16)(r >> 16);
}
__device__ __forceinline__ float bf2f(u16 b) {
  union { unsigned u; float f; } v; v.u = ((unsigned)b) << 16;
  return v.f;
}
// HW packed fp32->bf16 RNE (ties-even, same as f2bf); a -> low 16, b -> high 16
__device__ __forceinline__ unsigned cvt2bf(float a, float b) {
  unsigned r;
  asm("v_cvt_pk_bf16_f32 %0, %1, %2" : "=v"(r) : "v"(a), "v"(b));
  return r;
}
__device__ __forceinline__ void glds16(const void* g, void* l) {
  __builtin_amdgcn_global_load_lds((const __attribute__((address_space(1))) void*)g,
                                   (__attribute__((address_space(3))) void*)l, 16, 0, 0);
}

// ---------------------------------------------------------------- cast fp32->bf16
// Block-region mapping: all region boundaries are multiples of 4096 float4
// units, so each of the 3072 blocks handles 4096 units of exactly one tensor
// (x:512, wq:1024, wk:256, wv:256, wo:1024 blocks). No per-iteration branch,
// no grid-stride; 16 unrolled coalesced iters/thread. HBM roofline ~48us.
__global__ void cast_all(const float* __restrict__ x, const float* __restrict__ wq,
                         const float* __restrict__ wk, const float* __restrict__ wv,
                         const float* __restrict__ wo,
                         u16* __restrict__ xb, u16* __restrict__ wqb,
                         u16* __restrict__ wkb, u16* __restrict__ wvb,
                         u16* __restrict__ wob) {
  const int bid = blockIdx.x;
  const float* in; u16* outp; size_t base;
  if (bid < 512)       { in = x;  outp = xb;  base = (size_t)bid * 4096; }
  else if (bid < 1536) { in = wq; outp = wqb; base = (size_t)(bid - 512) * 4096; }
  else if (bid < 1792) { in = wk; outp = wkb; base = (size_t)(bid - 1536) * 4096; }
  else if (bid < 2048) { in = wv; outp = wvb; base = (size_t)(bid - 1792) * 4096; }
  else                 { in = wo; outp = wob; base = (size_t)(bid - 2048) * 4096; }
#pragma unroll
  for (int j = 0; j < 16; ++j) {
    const size_t i = base + j * 256 + threadIdx.x;
    float4 f = ((const float4*)in)[i];
    ushort4 b;
    b.x = f2bf(f.x); b.y = f2bf(f.y); b.z = f2bf(f.z); b.w = f2bf(f.w);
    ((ushort4*)outp)[i] = b;
  }
}

// ---------------------------------------------------------------- 2-phase GEMM, BM=128, BN=64*NF
// (R15 form verbatim — session-best: QKV ~104us, O ~70us, MfmaUtil 44%,
// 0 conflicts. Eight structural alternates (8-phase@1blk, wide-tile@1wave,
// fp32-reg-B, counted-vmcnt BK=32, single-buf@4blk, ...) all regressed;
// dbuf + 2 blocks/CU + 2 waves/SIMD is the proven optimum for this shape.)
template<int UN>
__device__ __forceinline__ void stage_t(const u16* __restrict__ g, int ldg, int k0,
                                        u16* ldsp, int t) {
  const int wb = t & ~63;
#pragma unroll
  for (int j = 0; j < UN / 256; ++j) {
    const int U = j * 256 + t;
    const int row = U >> 3, u = U & 7;
    const int uu = u ^ (row & 7);
    glds16(g + (size_t)row * ldg + k0 + uu * 8, ldsp + (size_t)(j * 256 + wb) * 8);
  }
}

template<int NF, bool QKV3>
__global__ __launch_bounds__(256, 2)
void gemm2p(const u16* __restrict__ A, const u16* __restrict__ B,
            void* __restrict__ Cq, u16* __restrict__ Ck, u16* __restrict__ Cv,
            int K) {
  constexpr int BN = 64 * NF;
  constexpr int AT = 128 * 64;        // u16 per A tile (8192)
  constexpr int BT = BN * 64;         // u16 per B tile
  __shared__ u16 lds[2 * (AT + BT)];  // A0 @0, A1 @AT, B0 @2*AT, B1 @2*AT+BT
  const int t = threadIdx.x;
  const int l = t & 63, lr = l & 15, lg = l >> 4;
  const int wid = t >> 6, wm = wid >> 1, wn = wid & 1;

  const int bid = blockIdx.x;
  const int xcd = bid & 7, j = bid >> 3;
  const int bx = xcd * 4 + (j >> 4);
  const int by = j & 15;
  const int m0 = by * 128, n0 = bx * BN;
  const int KT = K >> 6;

  const u16* Ab = A + (size_t)m0 * K;
  const u16* Bb = B + (size_t)n0 * K;

  f32x4 acc[4][2 * NF] = {};

  stage_t<1024>(Ab, K, 0, &lds[0], t);
  stage_t<BT / 8>(Bb, K, 0, &lds[2 * AT], t);
  __syncthreads();

  int cur = 0;
#pragma unroll 1
  for (int tau = 0; tau < KT; ++tau) {
    const int kn = (tau + 1 < KT ? tau + 1 : KT - 1) * 64;
    stage_t<1024>(Ab, K, kn, &lds[(cur ^ 1) * AT], t);
    stage_t<BT / 8>(Bb, K, kn, &lds[2 * AT + (cur ^ 1) * BT], t);

    const int aBase = cur * AT;
    const int bBase = 2 * AT + cur * BT;

    bf16x8 af[4][2];
#pragma unroll
    for (int mf = 0; mf < 4; ++mf)
#pragma unroll
      for (int kk = 0; kk < 2; ++kk) {
        const int row = wm * 64 + mf * 16 + lr;
        const int uu = ((kk * 4 + lg) ^ (row & 7)) * 8;
        af[mf][kk] = *(const bf16x8*)&lds[aBase + row * 64 + uu];
      }

#pragma unroll
    for (int n = 0; n < 2 * NF; ++n) {
      const int brow = wn * (32 * NF) + n * 16 + lr;
      const int u0 = ((0 * 4 + lg) ^ (brow & 7)) * 8;
      const int u1 = ((1 * 4 + lg) ^ (brow & 7)) * 8;
      bf16x8 b0 = *(const bf16x8*)&lds[bBase + brow * 64 + u0];
      bf16x8 b1 = *(const bf16x8*)&lds[bBase + brow * 64 + u1];
#pragma unroll
      for (int mf = 0; mf < 4; ++mf) {
        acc[mf][n] = __builtin_amdgcn_mfma_f32_16x16x32_bf16(af[mf][0], b0, acc[mf][n], 0, 0, 0);
        acc[mf][n] = __builtin_amdgcn_mfma_f32_16x16x32_bf16(af[mf][1], b1, acc[mf][n], 0, 0, 0);
      }
    }
    __syncthreads();
    cur ^= 1;
  }

  // epilogue; fragment cols are 16-aligned so QKV routing is per-fragment
#pragma unroll
  for (int mf = 0; mf < 4; ++mf) {
    const int row = m0 + wm * 64 + mf * 16 + lg * 4;
#pragma unroll
    for (int n = 0; n < 2 * NF; ++n) {
      const int gc = n0 + wn * (32 * NF) + n * 16 + lr;
#pragma unroll
      for (int r = 0; r < 4; ++r) {
        if constexpr (QKV3) {
          if (gc < 4096)
            ((u16*)Cq)[(size_t)(row + r) * 4096 + gc] = f2bf(acc[mf][n][r]);
          else if (gc < 5120)
            Ck[(size_t)(row + r) * 1024 + (gc - 4096)] = f2bf(acc[mf][n][r]);
          else
            Cv[(size_t)(row + r) * 1024 + (gc - 5120)] = f2bf(acc[mf][n][r]);
        } else {
          ((float*)Cq)[(size_t)(row + r) * 4096 + gc] = acc[mf][n][r];
        }
      }
    }
  }
}

// ---------------------------------------------------------------- fused RoPE + V-transpose
__global__ void rope_tr(u16* __restrict__ qd, u16* __restrict__ kd,
                        const float* __restrict__ cosb, const float* __restrict__ sinb,
                        const int* __restrict__ sidx,
                        const u16* __restrict__ v, u16* __restrict__ vt) {
  const int bid = blockIdx.x, t = threadIdx.x;
  if (bid < 5120) {
    const int u = bid * 256 + t;
    u16* base; int s, b;
    if (u < 1048576) {
      base = qd + (size_t)u * 8;
      s = u >> 9;
      b = u & 15;
    } else {
      const int u2 = u - 1048576;
      base = kd + (size_t)u2 * 8;
      s = u2 >> 7;
      b = u2 & 15;
    }
    const int pos = sidx[s];
    const float4 c  = *(const float4*)&cosb[pos * 64 + b * 4];
    const float4 sn = *(const float4*)&sinb[pos * 64 + b * 4];
    uint4 raw = *(uint4*)base;
    u16* pe = (u16*)&raw;
    const float cc[4] = {c.x, c.y, c.z, c.w};
    const float ss[4] = {sn.x, sn.y, sn.z, sn.w};
#pragma unroll
    for (int j = 0; j < 4; ++j) {
      const float xr = bf2f(pe[2 * j]), xi = bf2f(pe[2 * j + 1]);
      pe[2 * j]     = f2bf(xr * cc[j] - xi * ss[j]);
      pe[2 * j + 1] = f2bf(xr * ss[j] + xi * cc[j]);
    }
    *(uint4*)base = raw;
  } else {
    __shared__ u16 tile[32][33];
    const int tb = bid - 5120;
    const int c0 = (tb & 31) * 32, s0 = (tb >> 5) * 32;
    const int tx = t & 31, ty = t >> 5;   // 32 x 8
#pragma unroll
    for (int j = 0; j < 32; j += 8)
      tile[ty + j][tx] = v[(size_t)(s0 + ty + j) * EKV + c0 + tx];
    __syncthreads();
#pragma unroll
    for (int j = 0; j < 32; j += 8)
      vt[(size_t)(c0 + ty + j) * S_LEN + s0 + tx] = tile[tx][ty + j];
  }
}

// ---------------------------------------------------------------- flash attention
// (R15 form verbatim, measured ~55us: split causal pairing, single-buffered
// K/V 41.6 KB -> 3 blocks/CU, swapped QK^T with in-register softmax.)
#define ATTN_STAGE(TK) { \
  const int kv0s = (TK) * 64; \
  _Pragma("unroll") \
  for (int hh = 0; hh < 4; ++hh) { \
    const int f = hh * 256 + t; \
    { const int row = f >> 4, uu = f & 15, us = uu ^ (row & 7); \
      glds16(&k[(size_t)(kv0s + row) * EKV + kvh * HDIM + us * 8], &lK[(hh * 256 + wb) * 8]); } \
    { const int row = f >> 3, uu = f & 7, us = uu ^ (row & 7); \
      glds16(&vt[(size_t)(kvh * HDIM + row) * S_LEN + kv0s + us * 8], &lV[(hh * 256 + wb) * 8]); } \
  } }

__global__ __launch_bounds__(256, 3)
void attn_fwd(const u16* __restrict__ q, const u16* __restrict__ k,
              const u16* __restrict__ vt, u16* __restrict__ ao) {
  __shared__ u16 lK[64 * 128];
  __shared__ u16 lV[128 * 64];
  __shared__ u16 lP[4 * 16 * 72];
  const int t = threadIdx.x, w = t >> 6, l = t & 63;
  const int lr = l & 15, lg = l >> 4;
  const int wb = t & ~63;
  const int p = blockIdx.x, h = blockIdx.y;
  const int kvh = h >> 2;
  u16* lPw = &lP[w * (16 * 72)];

#pragma unroll 1
  for (int ph = 0; ph < 2; ++ph) {
    const int qt = ph ? (31 - p) : p;
    const int q0 = qt * 64 + w * 16;
    const int nt = qt + 1;

    bf16x8 qa[4];
#pragma unroll
    for (int kc = 0; kc < 4; ++kc)
      qa[kc] = *(const bf16x8*)&q[(size_t)(q0 + lr) * EQ + h * HDIM + kc * 32 + lg * 8];

    f32x4 o[8] = {};
    float mrun = -1e30f, lrun = 0.f;   // per-lane: q = q0 + lr

#pragma unroll 1
    for (int tk = 0; tk < nt; ++tk) {
      const int kv0 = tk * 64;
      __syncthreads();                 // prior compute done reading LDS
      ATTN_STAGE(tk);
      __syncthreads();                 // stage drained (vmcnt(0) implicit)

      // swapped QK^T: sc[n] has q = lr, kv = kv0 + n*16 + lg*4 + r
      f32x4 sc[4] = {};
#pragma unroll
      for (int n = 0; n < 4; ++n) {
#pragma unroll
        for (int kc = 0; kc < 4; ++kc) {
          const int row = n * 16 + lr;
          const int us = (kc * 4 + lg) ^ (row & 7);
          bf16x8 bk = *(const bf16x8*)&lK[row * 128 + us * 8];
          sc[n] = __builtin_amdgcn_mfma_f32_16x16x32_bf16(bk, qa[kc], sc[n], 0, 0, 0);
        }
      }

      // mask + scale (log2 domain)
      const int qr = q0 + lr;
#pragma unroll
      for (int n = 0; n < 4; ++n)
#pragma unroll
        for (int r = 0; r < 4; ++r) {
          const int kvc = kv0 + n * 16 + lg * 4 + r;
          const float vv = sc[n][r] * SC_LOG2E;
          sc[n][r] = (kvc > qr) ? -1e30f : vv;
        }

      // in-register row reduce (row = one q, spread over lanes lr, xor16/32)
      float vmx = sc[0][0];
#pragma unroll
      for (int n = 0; n < 4; ++n)
#pragma unroll
        for (int r = 0; r < 4; ++r) vmx = fmaxf(vmx, sc[n][r]);
      vmx = fmaxf(vmx, __shfl_xor(vmx, 16));
      vmx = fmaxf(vmx, __shfl_xor(vmx, 32));
      const float mn = fmaxf(mrun, vmx);
      const float sf = __builtin_amdgcn_exp2f(mrun - mn);
      mrun = mn;
      float rs = 0.f;
#pragma unroll
      for (int n = 0; n < 4; ++n)
#pragma unroll
        for (int r = 0; r < 4; ++r) {
          const float pv = __builtin_amdgcn_exp2f(sc[n][r] - mn);
          sc[n][r] = pv;
          rs += pv;
        }
      rs += __shfl_xor(rs, 16);
      rs += __shfl_xor(rs, 32);
      lrun = lrun * sf + rs;

      // o rescale: o[nh][r] sits at q = lg*4 + r -> fetch sf from lane lg*4+r
      {
        const float s0 = __shfl(sf, lg * 4 + 0);
        const float s1 = __shfl(sf, lg * 4 + 1);
        const float s2 = __shfl(sf, lg * 4 + 2);
        const float s3 = __shfl(sf, lg * 4 + 3);
#pragma unroll
        for (int nh = 0; nh < 8; ++nh) {
          o[nh][0] *= s0; o[nh][1] *= s1; o[nh][2] *= s2; o[nh][3] *= s3;
        }
      }

      // P -> LDS: lane's 4 kv-contiguous values per n -> cvt_pk + ds_write_b64
#pragma unroll
      for (int n = 0; n < 4; ++n) {
        uint2 wpk;
        wpk.x = cvt2bf(sc[n][0], sc[n][1]);
        wpk.y = cvt2bf(sc[n][2], sc[n][3]);
        *(uint2*)&lPw[lr * 72 + n * 16 + lg * 4] = wpk;
      }

      // PV (unchanged): pa has q = lr rows, kv-contiguous k
#pragma unroll
      for (int kc2 = 0; kc2 < 2; ++kc2) {
        bf16x8 pa = *(const bf16x8*)&lPw[lr * 72 + kc2 * 32 + lg * 8];
#pragma unroll
        for (int nh = 0; nh < 8; ++nh) {
          const int row = nh * 16 + lr;
          const int us = (kc2 * 4 + lg) ^ (row & 7);
          bf16x8 bv = *(const bf16x8*)&lV[row * 64 + us * 8];
          o[nh] = __builtin_amdgcn_mfma_f32_16x16x32_bf16(pa, bv, o[nh], 0, 0, 0);
        }
      }
    }

    // lrun lives at q=lr; outputs need q=lg*4+r
    {
      const float l0 = __shfl(lrun, lg * 4 + 0), l1 = __shfl(lrun, lg * 4 + 1);
      const float l2 = __shfl(lrun, lg * 4 + 2), l3 = __shfl(lrun, lg * 4 + 3);
      const float rl[4] = {l0, l1, l2, l3};
#pragma unroll
      for (int nh = 0; nh < 8; ++nh)
#pragma unroll
        for (int r = 0; r < 4; ++r) {
          const float val = o[nh][r] / rl[r];
          ao[(size_t)(q0 + lg * 4 + r) * EQ + h * HDIM + nh * 16 + lr] = f2bf(val);
        }
    }
  }
}

// ---------------------------------------------------------------- launch
extern "C" void kernel_launch(void* const* d_in, const int* in_sizes, int n_in,
                              void* d_out, int out_size, void* d_ws, size_t ws_size,
                              hipStream_t stream) {
  (void)in_sizes; (void)n_in; (void)out_size; (void)ws_size;
  const float* x    = (const float*)d_in[0];
  const float* wq   = (const float*)d_in[1];
  const float* wk   = (const float*)d_in[2];
  const float* wv   = (const float*)d_in[3];
  const float* wo   = (const float*)d_in[4];
  const float* cosb = (const float*)d_in[7];
  const float* sinb = (const float*)d_in[8];
  const int*   sidx = (const int*)d_in[10];
  float* out = (float*)d_out;

  // workspace layout; wqb/wkb/wvb are contiguous so B_qkv = [wq;wk;wv]
  u16* ws  = (u16*)d_ws;
  u16* xb  = ws;                                  // 2048*4096
  u16* wqb = xb  + (size_t)S_LEN * DM;            // 4096*4096
  u16* wkb = wqb + (size_t)EQ * DM;               // 1024*4096
  u16* wvb = wkb + (size_t)EKV * DM;              // 1024*4096
  u16* wob = wvb + (size_t)EKV * DM;              // 4096*4096
  u16* qb  = wob + (size_t)DM * EQ;               // 2048*4096
  u16* kb  = qb  + (size_t)S_LEN * EQ;            // 2048*1024
  u16* vb  = kb  + (size_t)S_LEN * EKV;           // 2048*1024
  u16* vtb = vb  + (size_t)S_LEN * EKV;           // 1024*2048
  u16* aob = vtb + (size_t)S_LEN * EKV;           // 2048*4096

  cast_all<<<3072, 256, 0, stream>>>(x, wq, wk, wv, wo, xb, wqb, wkb, wvb, wob);
  // fused QKV projection: B = [wq;wk;wv] (6144 x 4096); 1D grid 512, XCD-swizzled
  gemm2p<3, true><<<512, 256, 0, stream>>>(xb, wqb, qb, kb, vb, DM);
  // fused RoPE(q,k) + V-transpose: one dispatch, 5120 + 2048 blocks
  rope_tr<<<7168, 256, 0, stream>>>(qb, kb, cosb, sinb, sidx, vb, vtb);
  attn_fwd<<<dim3(16, NH), 256, 0, stream>>>(qb, kb, vtb, aob);
  // O projection: 1D grid 512, XCD-swizzled
  gemm2p<2, false><<<512, 256, 0, stream>>>(aob, wob, out, nullptr, nullptr, EQ);
}

// Round 18
// 297.193 us; speedup vs baseline: 1.5508x; 1.0108x over previous
//
#include <hip/hip_runtime.h>
#include <cstdint>
#include <cstddef>

#define S_LEN 2048
#define DM    4096
#define NH    32
#define NKV   8
#define HDIM  128
#define EQ    4096   // NH*HDIM
#define EKV   1024   // NKV*HDIM
#define SC_LOG2E 0.1275325477889277f   // (1/sqrt(128)) * log2(e)

typedef unsigned short u16;
typedef short bf16x8 __attribute__((ext_vector_type(8)));
typedef float f32x4  __attribute__((ext_vector_type(4)));

__device__ __forceinline__ u16 f2bf(float f) {
  union { float f; unsigned u; } v; v.f = f;
  unsigned r = v.u + 0x7FFFu + ((v.u >> 16) & 1u);
  return (u16)(r >> 16);
}
__device__ __forceinline__ float bf2f(u16 b) {
  union { unsigned u; float f; } v; v.u = ((unsigned)b) << 16;
  return v.f;
}
// HW packed fp32->bf16 RNE (ties-even, same as f2bf); a -> low 16, b -> high 16
__device__ __forceinline__ unsigned cvt2bf(float a, float b) {
  unsigned r;
  asm("v_cvt_pk_bf16_f32 %0, %1, %2" : "=v"(r) : "v"(a), "v"(b));
  return r;
}
__device__ __forceinline__ void glds16(const void* g, void* l) {
  __builtin_amdgcn_global_load_lds((const __attribute__((address_space(1))) void*)g,
                                   (__attribute__((address_space(3))) void*)l, 16, 0, 0);
}

// ---------------------------------------------------------------- cast fp32->bf16
// Block-region mapping (R17, measured HBM-roofline ~50us).
__global__ void cast_all(const float* __restrict__ x, const float* __restrict__ wq,
                         const float* __restrict__ wk, const float* __restrict__ wv,
                         const float* __restrict__ wo,
                         u16* __restrict__ xb, u16* __restrict__ wqb,
                         u16* __restrict__ wkb, u16* __restrict__ wvb,
                         u16* __restrict__ wob) {
  const int bid = blockIdx.x;
  const float* in; u16* outp; size_t base;
  if (bid < 512)       { in = x;  outp = xb;  base = (size_t)bid * 4096; }
  else if (bid < 1536) { in = wq; outp = wqb; base = (size_t)(bid - 512) * 4096; }
  else if (bid < 1792) { in = wk; outp = wkb; base = (size_t)(bid - 1536) * 4096; }
  else if (bid < 2048) { in = wv; outp = wvb; base = (size_t)(bid - 1792) * 4096; }
  else                 { in = wo; outp = wob; base = (size_t)(bid - 2048) * 4096; }
#pragma unroll
  for (int j = 0; j < 16; ++j) {
    const size_t i = base + j * 256 + threadIdx.x;
    float4 f = ((const float4*)in)[i];
    ushort4 b;
    b.x = f2bf(f.x); b.y = f2bf(f.y); b.z = f2bf(f.z); b.w = f2bf(f.w);
    ((ushort4*)outp)[i] = b;
  }
}

// ---------------------------------------------------------------- 2-phase GEMM, BM=128, BN=64*NF
// (R15 form verbatim — session-best: QKV ~104us, O ~70us, MfmaUtil 44%,
// 0 conflicts. Eight structural alternates all regressed; dbuf + 2 blocks/CU
// + 2 waves/SIMD is the proven optimum for this shape.)
template<int UN>
__device__ __forceinline__ void stage_t(const u16* __restrict__ g, int ldg, int k0,
                                        u16* ldsp, int t) {
  const int wb = t & ~63;
#pragma unroll
  for (int j = 0; j < UN / 256; ++j) {
    const int U = j * 256 + t;
    const int row = U >> 3, u = U & 7;
    const int uu = u ^ (row & 7);
    glds16(g + (size_t)row * ldg + k0 + uu * 8, ldsp + (size_t)(j * 256 + wb) * 8);
  }
}

template<int NF, bool QKV3>
__global__ __launch_bounds__(256, 2)
void gemm2p(const u16* __restrict__ A, const u16* __restrict__ B,
            void* __restrict__ Cq, u16* __restrict__ Ck, u16* __restrict__ Cv,
            int K) {
  constexpr int BN = 64 * NF;
  constexpr int AT = 128 * 64;        // u16 per A tile (8192)
  constexpr int BT = BN * 64;         // u16 per B tile
  __shared__ u16 lds[2 * (AT + BT)];  // A0 @0, A1 @AT, B0 @2*AT, B1 @2*AT+BT
  const int t = threadIdx.x;
  const int l = t & 63, lr = l & 15, lg = l >> 4;
  const int wid = t >> 6, wm = wid >> 1, wn = wid & 1;

  const int bid = blockIdx.x;
  const int xcd = bid & 7, j = bid >> 3;
  const int bx = xcd * 4 + (j >> 4);
  const int by = j & 15;
  const int m0 = by * 128, n0 = bx * BN;
  const int KT = K >> 6;

  const u16* Ab = A + (size_t)m0 * K;
  const u16* Bb = B + (size_t)n0 * K;

  f32x4 acc[4][2 * NF] = {};

  stage_t<1024>(Ab, K, 0, &lds[0], t);
  stage_t<BT / 8>(Bb, K, 0, &lds[2 * AT], t);
  __syncthreads();

  int cur = 0;
#pragma unroll 1
  for (int tau = 0; tau < KT; ++tau) {
    const int kn = (tau + 1 < KT ? tau + 1 : KT - 1) * 64;
    stage_t<1024>(Ab, K, kn, &lds[(cur ^ 1) * AT], t);
    stage_t<BT / 8>(Bb, K, kn, &lds[2 * AT + (cur ^ 1) * BT], t);

    const int aBase = cur * AT;
    const int bBase = 2 * AT + cur * BT;

    bf16x8 af[4][2];
#pragma unroll
    for (int mf = 0; mf < 4; ++mf)
#pragma unroll
      for (int kk = 0; kk < 2; ++kk) {
        const int row = wm * 64 + mf * 16 + lr;
        const int uu = ((kk * 4 + lg) ^ (row & 7)) * 8;
        af[mf][kk] = *(const bf16x8*)&lds[aBase + row * 64 + uu];
      }

#pragma unroll
    for (int n = 0; n < 2 * NF; ++n) {
      const int brow = wn * (32 * NF) + n * 16 + lr;
      const int u0 = ((0 * 4 + lg) ^ (brow & 7)) * 8;
      const int u1 = ((1 * 4 + lg) ^ (brow & 7)) * 8;
      bf16x8 b0 = *(const bf16x8*)&lds[bBase + brow * 64 + u0];
      bf16x8 b1 = *(const bf16x8*)&lds[bBase + brow * 64 + u1];
#pragma unroll
      for (int mf = 0; mf < 4; ++mf) {
        acc[mf][n] = __builtin_amdgcn_mfma_f32_16x16x32_bf16(af[mf][0], b0, acc[mf][n], 0, 0, 0);
        acc[mf][n] = __builtin_amdgcn_mfma_f32_16x16x32_bf16(af[mf][1], b1, acc[mf][n], 0, 0, 0);
      }
    }
    __syncthreads();
    cur ^= 1;
  }

  // epilogue; fragment cols are 16-aligned so QKV routing is per-fragment
#pragma unroll
  for (int mf = 0; mf < 4; ++mf) {
    const int row = m0 + wm * 64 + mf * 16 + lg * 4;
#pragma unroll
    for (int n = 0; n < 2 * NF; ++n) {
      const int gc = n0 + wn * (32 * NF) + n * 16 + lr;
#pragma unroll
      for (int r = 0; r < 4; ++r) {
        if constexpr (QKV3) {
          if (gc < 4096)
            ((u16*)Cq)[(size_t)(row + r) * 4096 + gc] = f2bf(acc[mf][n][r]);
          else if (gc < 5120)
            Ck[(size_t)(row + r) * 1024 + (gc - 4096)] = f2bf(acc[mf][n][r]);
          else
            Cv[(size_t)(row + r) * 1024 + (gc - 5120)] = f2bf(acc[mf][n][r]);
        } else {
          ((float*)Cq)[(size_t)(row + r) * 4096 + gc] = acc[mf][n][r];
        }
      }
    }
  }
}

// ---------------------------------------------------------------- fused RoPE + V-transpose
__global__ void rope_tr(u16* __restrict__ qd, u16* __restrict__ kd,
                        const float* __restrict__ cosb, const float* __restrict__ sinb,
                        const int* __restrict__ sidx,
                        const u16* __restrict__ v, u16* __restrict__ vt) {
  const int bid = blockIdx.x, t = threadIdx.x;
  if (bid < 5120) {
    const int u = bid * 256 + t;
    u16* base; int s, b;
    if (u < 1048576) {
      base = qd + (size_t)u * 8;
      s = u >> 9;
      b = u & 15;
    } else {
      const int u2 = u - 1048576;
      base = kd + (size_t)u2 * 8;
      s = u2 >> 7;
      b = u2 & 15;
    }
    const int pos = sidx[s];
    const float4 c  = *(const float4*)&cosb[pos * 64 + b * 4];
    const float4 sn = *(const float4*)&sinb[pos * 64 + b * 4];
    uint4 raw = *(uint4*)base;
    u16* pe = (u16*)&raw;
    const float cc[4] = {c.x, c.y, c.z, c.w};
    const float ss[4] = {sn.x, sn.y, sn.z, sn.w};
#pragma unroll
    for (int j = 0; j < 4; ++j) {
      const float xr = bf2f(pe[2 * j]), xi = bf2f(pe[2 * j + 1]);
      pe[2 * j]     = f2bf(xr * cc[j] - xi * ss[j]);
      pe[2 * j + 1] = f2bf(xr * ss[j] + xi * cc[j]);
    }
    *(uint4*)base = raw;
  } else {
    __shared__ u16 tile[32][33];
    const int tb = bid - 5120;
    const int c0 = (tb & 31) * 32, s0 = (tb >> 5) * 32;
    const int tx = t & 31, ty = t >> 5;   // 32 x 8
#pragma unroll
    for (int j = 0; j < 32; j += 8)
      tile[ty + j][tx] = v[(size_t)(s0 + ty + j) * EKV + c0 + tx];
    __syncthreads();
#pragma unroll
    for (int j = 0; j < 32; j += 8)
      vt[(size_t)(c0 + ty + j) * S_LEN + s0 + tx] = tile[tx][ty + j];
  }
}

// ---------------------------------------------------------------- flash attention
// R15 structure (split causal pairing, single-buffered K/V 41.6 KB ->
// 3 blocks/CU, swapped QK^T with in-register softmax) + T13 DEFER-MAX:
// when __all(vmx <= mrun + 8) (wave-uniform), keep the old running max —
// P = exp2(sc - mrun) <= 2^8 = 256 (bf16-safe; lrun fp32 <= 2048*256) and
// the sf exp + 4 shfl broadcasts + 32 o-multiplies are skipped (~95% of
// tile-steps after warmup). o/lrun stay consistently scaled.
#define ATTN_STAGE(TK) { \
  const int kv0s = (TK) * 64; \
  _Pragma("unroll") \
  for (int hh = 0; hh < 4; ++hh) { \
    const int f = hh * 256 + t; \
    { const int row = f >> 4, uu = f & 15, us = uu ^ (row & 7); \
      glds16(&k[(size_t)(kv0s + row) * EKV + kvh * HDIM + us * 8], &lK[(hh * 256 + wb) * 8]); } \
    { const int row = f >> 3, uu = f & 7, us = uu ^ (row & 7); \
      glds16(&vt[(size_t)(kvh * HDIM + row) * S_LEN + kv0s + us * 8], &lV[(hh * 256 + wb) * 8]); } \
  } }

__global__ __launch_bounds__(256, 3)
void attn_fwd(const u16* __restrict__ q, const u16* __restrict__ k,
              const u16* __restrict__ vt, u16* __restrict__ ao) {
  __shared__ u16 lK[64 * 128];
  __shared__ u16 lV[128 * 64];
  __shared__ u16 lP[4 * 16 * 72];
  const int t = threadIdx.x, w = t >> 6, l = t & 63;
  const int lr = l & 15, lg = l >> 4;
  const int wb = t & ~63;
  const int p = blockIdx.x, h = blockIdx.y;
  const int kvh = h >> 2;
  u16* lPw = &lP[w * (16 * 72)];

#pragma unroll 1
  for (int ph = 0; ph < 2; ++ph) {
    const int qt = ph ? (31 - p) : p;
    const int q0 = qt * 64 + w * 16;
    const int nt = qt + 1;

    bf16x8 qa[4];
#pragma unroll
    for (int kc = 0; kc < 4; ++kc)
      qa[kc] = *(const bf16x8*)&q[(size_t)(q0 + lr) * EQ + h * HDIM + kc * 32 + lg * 8];

    f32x4 o[8] = {};
    float mrun = -1e30f, lrun = 0.f;   // per-lane: q = q0 + lr

#pragma unroll 1
    for (int tk = 0; tk < nt; ++tk) {
      const int kv0 = tk * 64;
      __syncthreads();                 // prior compute done reading LDS
      ATTN_STAGE(tk);
      __syncthreads();                 // stage drained (vmcnt(0) implicit)

      // swapped QK^T: sc[n] has q = lr, kv = kv0 + n*16 + lg*4 + r
      f32x4 sc[4] = {};
#pragma unroll
      for (int n = 0; n < 4; ++n) {
#pragma unroll
        for (int kc = 0; kc < 4; ++kc) {
          const int row = n * 16 + lr;
          const int us = (kc * 4 + lg) ^ (row & 7);
          bf16x8 bk = *(const bf16x8*)&lK[row * 128 + us * 8];
          sc[n] = __builtin_amdgcn_mfma_f32_16x16x32_bf16(bk, qa[kc], sc[n], 0, 0, 0);
        }
      }

      // mask + scale (log2 domain)
      const int qr = q0 + lr;
#pragma unroll
      for (int n = 0; n < 4; ++n)
#pragma unroll
        for (int r = 0; r < 4; ++r) {
          const int kvc = kv0 + n * 16 + lg * 4 + r;
          const float vv = sc[n][r] * SC_LOG2E;
          sc[n][r] = (kvc > qr) ? -1e30f : vv;
        }

      // in-register row reduce (row = one q, spread over lanes lr, xor16/32)
      float vmx = sc[0][0];
#pragma unroll
      for (int n = 0; n < 4; ++n)
#pragma unroll
        for (int r = 0; r < 4; ++r) vmx = fmaxf(vmx, sc[n][r]);
      vmx = fmaxf(vmx, __shfl_xor(vmx, 16));
      vmx = fmaxf(vmx, __shfl_xor(vmx, 32));

      // T13 defer-max: wave-uniform skip of the rescale when max growth <= 8
      const bool noscale = __all(vmx <= mrun + 8.0f);
      float sf = 0.f;
      if (!noscale) {
        const float mn2 = fmaxf(mrun, vmx);
        sf = __builtin_amdgcn_exp2f(mrun - mn2);
        mrun = mn2;
      }
      const float mn = mrun;

      float rs = 0.f;
#pragma unroll
      for (int n = 0; n < 4; ++n)
#pragma unroll
        for (int r = 0; r < 4; ++r) {
          const float pv = __builtin_amdgcn_exp2f(sc[n][r] - mn);
          sc[n][r] = pv;
          rs += pv;
        }
      rs += __shfl_xor(rs, 16);
      rs += __shfl_xor(rs, 32);

      if (noscale) {
        lrun += rs;
      } else {
        lrun = lrun * sf + rs;
        // o rescale: o[nh][r] sits at q = lg*4 + r -> fetch sf from lane lg*4+r
        const float s0 = __shfl(sf, lg * 4 + 0);
        const float s1 = __shfl(sf, lg * 4 + 1);
        const float s2 = __shfl(sf, lg * 4 + 2);
        const float s3 = __shfl(sf, lg * 4 + 3);
#pragma unroll
        for (int nh = 0; nh < 8; ++nh) {
          o[nh][0] *= s0; o[nh][1] *= s1; o[nh][2] *= s2; o[nh][3] *= s3;
        }
      }

      // P -> LDS: lane's 4 kv-contiguous values per n -> cvt_pk + ds_write_b64
#pragma unroll
      for (int n = 0; n < 4; ++n) {
        uint2 wpk;
        wpk.x = cvt2bf(sc[n][0], sc[n][1]);
        wpk.y = cvt2bf(sc[n][2], sc[n][3]);
        *(uint2*)&lPw[lr * 72 + n * 16 + lg * 4] = wpk;
      }

      // PV: pa has q = lr rows, kv-contiguous k
#pragma unroll
      for (int kc2 = 0; kc2 < 2; ++kc2) {
        bf16x8 pa = *(const bf16x8*)&lPw[lr * 72 + kc2 * 32 + lg * 8];
#pragma unroll
        for (int nh = 0; nh < 8; ++nh) {
          const int row = nh * 16 + lr;
          const int us = (kc2 * 4 + lg) ^ (row & 7);
          bf16x8 bv = *(const bf16x8*)&lV[row * 64 + us * 8];
          o[nh] = __builtin_amdgcn_mfma_f32_16x16x32_bf16(pa, bv, o[nh], 0, 0, 0);
        }
      }
    }

    // lrun lives at q=lr; outputs need q=lg*4+r
    {
      const float l0 = __shfl(lrun, lg * 4 + 0), l1 = __shfl(lrun, lg * 4 + 1);
      const float l2 = __shfl(lrun, lg * 4 + 2), l3 = __shfl(lrun, lg * 4 + 3);
      const float rl[4] = {l0, l1, l2, l3};
#pragma unroll
      for (int nh = 0; nh < 8; ++nh)
#pragma unroll
        for (int r = 0; r < 4; ++r) {
          const float val = o[nh][r] / rl[r];
          ao[(size_t)(q0 + lg * 4 + r) * EQ + h * HDIM + nh * 16 + lr] = f2bf(val);
        }
    }
  }
}

// ---------------------------------------------------------------- launch
extern "C" void kernel_launch(void* const* d_in, const int* in_sizes, int n_in,
                              void* d_out, int out_size, void* d_ws, size_t ws_size,
                              hipStream_t stream) {
  (void)in_sizes; (void)n_in; (void)out_size; (void)ws_size;
  const float* x    = (const float*)d_in[0];
  const float* wq   = (const float*)d_in[1];
  const float* wk   = (const float*)d_in[2];
  const float* wv   = (const float*)d_in[3];
  const float* wo   = (const float*)d_in[4];
  const float* cosb = (const float*)d_in[7];
  const float* sinb = (const float*)d_in[8];
  const int*   sidx = (const int*)d_in[10];
  float* out = (float*)d_out;

  // workspace layout; wqb/wkb/wvb are contiguous so B_qkv = [wq;wk;wv]
  u16* ws  = (u16*)d_ws;
  u16* xb  = ws;                                  // 2048*4096
  u16* wqb = xb  + (size_t)S_LEN * DM;            // 4096*4096
  u16* wkb = wqb + (size_t)EQ * DM;               // 1024*4096
  u16* wvb = wkb + (size_t)EKV * DM;              // 1024*4096
  u16* wob = wvb + (size_t)EKV * DM;              // 4096*4096
  u16* qb  = wob + (size_t)DM * EQ;               // 2048*4096
  u16* kb  = qb  + (size_t)S_LEN * EQ;            // 2048*1024
  u16* vb  = kb  + (size_t)S_LEN * EKV;           // 2048*1024
  u16* vtb = vb  + (size_t)S_LEN * EKV;           // 1024*2048
  u16* aob = vtb + (size_t)S_LEN * EKV;           // 2048*4096

  cast_all<<<3072, 256, 0, stream>>>(x, wq, wk, wv, wo, xb, wqb, wkb, wvb, wob);
  // fused QKV projection: B = [wq;wk;wv] (6144 x 4096); 1D grid 512, XCD-swizzled
  gemm2p<3, true><<<512, 256, 0, stream>>>(xb, wqb, qb, kb, vb, DM);
  // fused RoPE(q,k) + V-transpose: one dispatch, 5120 + 2048 blocks
  rope_tr<<<7168, 256, 0, stream>>>(qb, kb, cosb, sinb, sidx, vb, vtb);
  attn_fwd<<<dim3(16, NH), 256, 0, stream>>>(qb, kb, vtb, aob);
  // O projection: 1D grid 512, XCD-swizzled
  gemm2p<2, false><<<512, 256, 0, stream>>>(aob, wob, out, nullptr, nullptr, EQ);
}

// Round 19
// 294.112 us; speedup vs baseline: 1.5670x; 1.0105x over previous
//
#include <hip/hip_runtime.h>
#include <cstdint>
#include <cstddef>

#define S_LEN 2048
#define DM    4096
#define NH    32
#define NKV   8
#define HDIM  128
#define EQ    4096   // NH*HDIM
#define EKV   1024   // NKV*HDIM
#define SC_LOG2E 0.1275325477889277f   // (1/sqrt(128)) * log2(e)

typedef unsigned short u16;
typedef short bf16x8 __attribute__((ext_vector_type(8)));
typedef float f32x4  __attribute__((ext_vector_type(4)));

__device__ __forceinline__ u16 f2bf(float f) {
  union { float f; unsigned u; } v; v.f = f;
  unsigned r = v.u + 0x7FFFu + ((v.u >> 16) & 1u);
  return (u16)(r >> 16);
}
__device__ __forceinline__ float bf2f(u16 b) {
  union { unsigned u; float f; } v; v.u = ((unsigned)b) << 16;
  return v.f;
}
// HW packed fp32->bf16 RNE (ties-even, same as f2bf); a -> low 16, b -> high 16
__device__ __forceinline__ unsigned cvt2bf(float a, float b) {
  unsigned r;
  asm("v_cvt_pk_bf16_f32 %0, %1, %2" : "=v"(r) : "v"(a), "v"(b));
  return r;
}
__device__ __forceinline__ void glds16(const void* g, void* l) {
  __builtin_amdgcn_global_load_lds((const __attribute__((address_space(1))) void*)g,
                                   (__attribute__((address_space(3))) void*)l, 16, 0, 0);
}

// ---------------------------------------------------------------- cast fp32->bf16
// Block-region mapping (R17, measured HBM-roofline ~50us).
__global__ void cast_all(const float* __restrict__ x, const float* __restrict__ wq,
                         const float* __restrict__ wk, const float* __restrict__ wv,
                         const float* __restrict__ wo,
                         u16* __restrict__ xb, u16* __restrict__ wqb,
                         u16* __restrict__ wkb, u16* __restrict__ wvb,
                         u16* __restrict__ wob) {
  const int bid = blockIdx.x;
  const float* in; u16* outp; size_t base;
  if (bid < 512)       { in = x;  outp = xb;  base = (size_t)bid * 4096; }
  else if (bid < 1536) { in = wq; outp = wqb; base = (size_t)(bid - 512) * 4096; }
  else if (bid < 1792) { in = wk; outp = wkb; base = (size_t)(bid - 1536) * 4096; }
  else if (bid < 2048) { in = wv; outp = wvb; base = (size_t)(bid - 1792) * 4096; }
  else                 { in = wo; outp = wob; base = (size_t)(bid - 2048) * 4096; }
#pragma unroll
  for (int j = 0; j < 16; ++j) {
    const size_t i = base + j * 256 + threadIdx.x;
    float4 f = ((const float4*)in)[i];
    ushort4 b;
    b.x = f2bf(f.x); b.y = f2bf(f.y); b.z = f2bf(f.z); b.w = f2bf(f.w);
    ((ushort4*)outp)[i] = b;
  }
}

// ---------------------------------------------------------------- 2-phase GEMM, BM=128, BN=64*NF
// (R15 form verbatim — session-best: QKV ~102us, O ~70us, MfmaUtil 44%,
// 0 conflicts. Eight structural alternates all regressed; dbuf + 2 blocks/CU
// + 2 waves/SIMD is the proven optimum for this shape.)
template<int UN>
__device__ __forceinline__ void stage_t(const u16* __restrict__ g, int ldg, int k0,
                                        u16* ldsp, int t) {
  const int wb = t & ~63;
#pragma unroll
  for (int j = 0; j < UN / 256; ++j) {
    const int U = j * 256 + t;
    const int row = U >> 3, u = U & 7;
    const int uu = u ^ (row & 7);
    glds16(g + (size_t)row * ldg + k0 + uu * 8, ldsp + (size_t)(j * 256 + wb) * 8);
  }
}

template<int NF, bool QKV3>
__global__ __launch_bounds__(256, 2)
void gemm2p(const u16* __restrict__ A, const u16* __restrict__ B,
            void* __restrict__ Cq, u16* __restrict__ Ck, u16* __restrict__ Cv,
            int K) {
  constexpr int BN = 64 * NF;
  constexpr int AT = 128 * 64;        // u16 per A tile (8192)
  constexpr int BT = BN * 64;         // u16 per B tile
  __shared__ u16 lds[2 * (AT + BT)];  // A0 @0, A1 @AT, B0 @2*AT, B1 @2*AT+BT
  const int t = threadIdx.x;
  const int l = t & 63, lr = l & 15, lg = l >> 4;
  const int wid = t >> 6, wm = wid >> 1, wn = wid & 1;

  const int bid = blockIdx.x;
  const int xcd = bid & 7, j = bid >> 3;
  const int bx = xcd * 4 + (j >> 4);
  const int by = j & 15;
  const int m0 = by * 128, n0 = bx * BN;
  const int KT = K >> 6;

  const u16* Ab = A + (size_t)m0 * K;
  const u16* Bb = B + (size_t)n0 * K;

  f32x4 acc[4][2 * NF] = {};

  stage_t<1024>(Ab, K, 0, &lds[0], t);
  stage_t<BT / 8>(Bb, K, 0, &lds[2 * AT], t);
  __syncthreads();

  int cur = 0;
#pragma unroll 1
  for (int tau = 0; tau < KT; ++tau) {
    const int kn = (tau + 1 < KT ? tau + 1 : KT - 1) * 64;
    stage_t<1024>(Ab, K, kn, &lds[(cur ^ 1) * AT], t);
    stage_t<BT / 8>(Bb, K, kn, &lds[2 * AT + (cur ^ 1) * BT], t);

    const int aBase = cur * AT;
    const int bBase = 2 * AT + cur * BT;

    bf16x8 af[4][2];
#pragma unroll
    for (int mf = 0; mf < 4; ++mf)
#pragma unroll
      for (int kk = 0; kk < 2; ++kk) {
        const int row = wm * 64 + mf * 16 + lr;
        const int uu = ((kk * 4 + lg) ^ (row & 7)) * 8;
        af[mf][kk] = *(const bf16x8*)&lds[aBase + row * 64 + uu];
      }

#pragma unroll
    for (int n = 0; n < 2 * NF; ++n) {
      const int brow = wn * (32 * NF) + n * 16 + lr;
      const int u0 = ((0 * 4 + lg) ^ (brow & 7)) * 8;
      const int u1 = ((1 * 4 + lg) ^ (brow & 7)) * 8;
      bf16x8 b0 = *(const bf16x8*)&lds[bBase + brow * 64 + u0];
      bf16x8 b1 = *(const bf16x8*)&lds[bBase + brow * 64 + u1];
#pragma unroll
      for (int mf = 0; mf < 4; ++mf) {
        acc[mf][n] = __builtin_amdgcn_mfma_f32_16x16x32_bf16(af[mf][0], b0, acc[mf][n], 0, 0, 0);
        acc[mf][n] = __builtin_amdgcn_mfma_f32_16x16x32_bf16(af[mf][1], b1, acc[mf][n], 0, 0, 0);
      }
    }
    __syncthreads();
    cur ^= 1;
  }

  // epilogue; fragment cols are 16-aligned so QKV routing is per-fragment
#pragma unroll
  for (int mf = 0; mf < 4; ++mf) {
    const int row = m0 + wm * 64 + mf * 16 + lg * 4;
#pragma unroll
    for (int n = 0; n < 2 * NF; ++n) {
      const int gc = n0 + wn * (32 * NF) + n * 16 + lr;
#pragma unroll
      for (int r = 0; r < 4; ++r) {
        if constexpr (QKV3) {
          if (gc < 4096)
            ((u16*)Cq)[(size_t)(row + r) * 4096 + gc] = f2bf(acc[mf][n][r]);
          else if (gc < 5120)
            Ck[(size_t)(row + r) * 1024 + (gc - 4096)] = f2bf(acc[mf][n][r]);
          else
            Cv[(size_t)(row + r) * 1024 + (gc - 5120)] = f2bf(acc[mf][n][r]);
        } else {
          ((float*)Cq)[(size_t)(row + r) * 4096 + gc] = acc[mf][n][r];
        }
      }
    }
  }
}

// ---------------------------------------------------------------- fused k-RoPE + V-transpose
// q-RoPE is folded into attn_fwd's q-load (in-register, same fp32 math + RNE
// rounding -> bit-identical). Blocks [0,1024) = k rope (262144 units);
// [1024,3072) = 32x32 transpose tiles of v -> vt.
__global__ void rope_tr(u16* __restrict__ kd,
                        const float* __restrict__ cosb, const float* __restrict__ sinb,
                        const int* __restrict__ sidx,
                        const u16* __restrict__ v, u16* __restrict__ vt) {
  const int bid = blockIdx.x, t = threadIdx.x;
  if (bid < 1024) {
    const int u2 = bid * 256 + t;
    u16* base = kd + (size_t)u2 * 8;
    const int s = u2 >> 7;           // (u2>>4)/NKV
    const int b = u2 & 15;
    const int pos = sidx[s];
    const float4 c  = *(const float4*)&cosb[pos * 64 + b * 4];
    const float4 sn = *(const float4*)&sinb[pos * 64 + b * 4];
    uint4 raw = *(uint4*)base;
    u16* pe = (u16*)&raw;
    const float cc[4] = {c.x, c.y, c.z, c.w};
    const float ss[4] = {sn.x, sn.y, sn.z, sn.w};
#pragma unroll
    for (int j = 0; j < 4; ++j) {
      const float xr = bf2f(pe[2 * j]), xi = bf2f(pe[2 * j + 1]);
      pe[2 * j]     = f2bf(xr * cc[j] - xi * ss[j]);
      pe[2 * j + 1] = f2bf(xr * ss[j] + xi * cc[j]);
    }
    *(uint4*)base = raw;
  } else {
    __shared__ u16 tile[32][33];
    const int tb = bid - 1024;
    const int c0 = (tb & 31) * 32, s0 = (tb >> 5) * 32;
    const int tx = t & 31, ty = t >> 5;   // 32 x 8
#pragma unroll
    for (int j = 0; j < 32; j += 8)
      tile[ty + j][tx] = v[(size_t)(s0 + ty + j) * EKV + c0 + tx];
    __syncthreads();
#pragma unroll
    for (int j = 0; j < 32; j += 8)
      vt[(size_t)(c0 + ty + j) * S_LEN + s0 + tx] = tile[tx][ty + j];
  }
}

// ---------------------------------------------------------------- flash attention
// R18 structure (split causal pairing, single-buffered K/V -> 3 blocks/CU,
// swapped QK^T, in-register softmax, T13 defer-max) + q-RoPE FOLDED into the
// q-load: each bf16x8 fragment holds 4 complete (even,odd) pairs; rotate with
// fp32 cos/sin once per q-tile, repack via cvt_pk (RNE — bit-identical to the
// old separate rope pass).
#define ATTN_STAGE(TK) { \
  const int kv0s = (TK) * 64; \
  _Pragma("unroll") \
  for (int hh = 0; hh < 4; ++hh) { \
    const int f = hh * 256 + t; \
    { const int row = f >> 4, uu = f & 15, us = uu ^ (row & 7); \
      glds16(&k[(size_t)(kv0s + row) * EKV + kvh * HDIM + us * 8], &lK[(hh * 256 + wb) * 8]); } \
    { const int row = f >> 3, uu = f & 7, us = uu ^ (row & 7); \
      glds16(&vt[(size_t)(kvh * HDIM + row) * S_LEN + kv0s + us * 8], &lV[(hh * 256 + wb) * 8]); } \
  } }

__global__ __launch_bounds__(256, 3)
void attn_fwd(const u16* __restrict__ q, const u16* __restrict__ k,
              const u16* __restrict__ vt, u16* __restrict__ ao,
              const float* __restrict__ cosb, const float* __restrict__ sinb,
              const int* __restrict__ sidx) {
  __shared__ u16 lK[64 * 128];
  __shared__ u16 lV[128 * 64];
  __shared__ u16 lP[4 * 16 * 72];
  const int t = threadIdx.x, w = t >> 6, l = t & 63;
  const int lr = l & 15, lg = l >> 4;
  const int wb = t & ~63;
  const int p = blockIdx.x, h = blockIdx.y;
  const int kvh = h >> 2;
  u16* lPw = &lP[w * (16 * 72)];

#pragma unroll 1
  for (int ph = 0; ph < 2; ++ph) {
    const int qt = ph ? (31 - p) : p;
    const int q0 = qt * 64 + w * 16;
    const int nt = qt + 1;

    // q-load + in-register RoPE (once per q-tile)
    const int pos = sidx[q0 + lr];
    bf16x8 qa[4];
#pragma unroll
    for (int kc = 0; kc < 4; ++kc) {
      bf16x8 raw = *(const bf16x8*)&q[(size_t)(q0 + lr) * EQ + h * HDIM + kc * 32 + lg * 8];
      const float4 c  = *(const float4*)&cosb[pos * 64 + kc * 16 + lg * 4];
      const float4 sn = *(const float4*)&sinb[pos * 64 + kc * 16 + lg * 4];
      const float cc[4] = {c.x, c.y, c.z, c.w};
      const float ss[4] = {sn.x, sn.y, sn.z, sn.w};
      unsigned pk[4];
#pragma unroll
      for (int jj = 0; jj < 4; ++jj) {
        const float xr = bf2f(((u16*)&raw)[2 * jj]);
        const float xi = bf2f(((u16*)&raw)[2 * jj + 1]);
        pk[jj] = cvt2bf(xr * cc[jj] - xi * ss[jj], xr * ss[jj] + xi * cc[jj]);
      }
      qa[kc] = *(bf16x8*)pk;
    }

    f32x4 o[8] = {};
    float mrun = -1e30f, lrun = 0.f;   // per-lane: q = q0 + lr

#pragma unroll 1
    for (int tk = 0; tk < nt; ++tk) {
      const int kv0 = tk * 64;
      __syncthreads();                 // prior compute done reading LDS
      ATTN_STAGE(tk);
      __syncthreads();                 // stage drained (vmcnt(0) implicit)

      // swapped QK^T: sc[n] has q = lr, kv = kv0 + n*16 + lg*4 + r
      f32x4 sc[4] = {};
#pragma unroll
      for (int n = 0; n < 4; ++n) {
#pragma unroll
        for (int kc = 0; kc < 4; ++kc) {
          const int row = n * 16 + lr;
          const int us = (kc * 4 + lg) ^ (row & 7);
          bf16x8 bk = *(const bf16x8*)&lK[row * 128 + us * 8];
          sc[n] = __builtin_amdgcn_mfma_f32_16x16x32_bf16(bk, qa[kc], sc[n], 0, 0, 0);
        }
      }

      // mask + scale (log2 domain)
      const int qr = q0 + lr;
#pragma unroll
      for (int n = 0; n < 4; ++n)
#pragma unroll
        for (int r = 0; r < 4; ++r) {
          const int kvc = kv0 + n * 16 + lg * 4 + r;
          const float vv = sc[n][r] * SC_LOG2E;
          sc[n][r] = (kvc > qr) ? -1e30f : vv;
        }

      // in-register row reduce (row = one q, spread over lanes lr, xor16/32)
      float vmx = sc[0][0];
#pragma unroll
      for (int n = 0; n < 4; ++n)
#pragma unroll
        for (int r = 0; r < 4; ++r) vmx = fmaxf(vmx, sc[n][r]);
      vmx = fmaxf(vmx, __shfl_xor(vmx, 16));
      vmx = fmaxf(vmx, __shfl_xor(vmx, 32));

      // T13 defer-max: wave-uniform skip of the rescale when max growth <= 8
      const bool noscale = __all(vmx <= mrun + 8.0f);
      float sf = 0.f;
      if (!noscale) {
        const float mn2 = fmaxf(mrun, vmx);
        sf = __builtin_amdgcn_exp2f(mrun - mn2);
        mrun = mn2;
      }
      const float mn = mrun;

      float rs = 0.f;
#pragma unroll
      for (int n = 0; n < 4; ++n)
#pragma unroll
        for (int r = 0; r < 4; ++r) {
          const float pv = __builtin_amdgcn_exp2f(sc[n][r] - mn);
          sc[n][r] = pv;
          rs += pv;
        }
      rs += __shfl_xor(rs, 16);
      rs += __shfl_xor(rs, 32);

      if (noscale) {
        lrun += rs;
      } else {
        lrun = lrun * sf + rs;
        // o rescale: o[nh][r] sits at q = lg*4 + r -> fetch sf from lane lg*4+r
        const float s0 = __shfl(sf, lg * 4 + 0);
        const float s1 = __shfl(sf, lg * 4 + 1);
        const float s2 = __shfl(sf, lg * 4 + 2);
        const float s3 = __shfl(sf, lg * 4 + 3);
#pragma unroll
        for (int nh = 0; nh < 8; ++nh) {
          o[nh][0] *= s0; o[nh][1] *= s1; o[nh][2] *= s2; o[nh][3] *= s3;
        }
      }

      // P -> LDS: lane's 4 kv-contiguous values per n -> cvt_pk + ds_write_b64
#pragma unroll
      for (int n = 0; n < 4; ++n) {
        uint2 wpk;
        wpk.x = cvt2bf(sc[n][0], sc[n][1]);
        wpk.y = cvt2bf(sc[n][2], sc[n][3]);
        *(uint2*)&lPw[lr * 72 + n * 16 + lg * 4] = wpk;
      }

      // PV: pa has q = lr rows, kv-contiguous k
#pragma unroll
      for (int kc2 = 0; kc2 < 2; ++kc2) {
        bf16x8 pa = *(const bf16x8*)&lPw[lr * 72 + kc2 * 32 + lg * 8];
#pragma unroll
        for (int nh = 0; nh < 8; ++nh) {
          const int row = nh * 16 + lr;
          const int us = (kc2 * 4 + lg) ^ (row & 7);
          bf16x8 bv = *(const bf16x8*)&lV[row * 64 + us * 8];
          o[nh] = __builtin_amdgcn_mfma_f32_16x16x32_bf16(pa, bv, o[nh], 0, 0, 0);
        }
      }
    }

    // lrun lives at q=lr; outputs need q=lg*4+r
    {
      const float l0 = __shfl(lrun, lg * 4 + 0), l1 = __shfl(lrun, lg * 4 + 1);
      const float l2 = __shfl(lrun, lg * 4 + 2), l3 = __shfl(lrun, lg * 4 + 3);
      const float rl[4] = {l0, l1, l2, l3};
#pragma unroll
      for (int nh = 0; nh < 8; ++nh)
#pragma unroll
        for (int r = 0; r < 4; ++r) {
          const float val = o[nh][r] / rl[r];
          ao[(size_t)(q0 + lg * 4 + r) * EQ + h * HDIM + nh * 16 + lr] = f2bf(val);
        }
    }
  }
}

// ---------------------------------------------------------------- launch
extern "C" void kernel_launch(void* const* d_in, const int* in_sizes, int n_in,
                              void* d_out, int out_size, void* d_ws, size_t ws_size,
                              hipStream_t stream) {
  (void)in_sizes; (void)n_in; (void)out_size; (void)ws_size;
  const float* x    = (const float*)d_in[0];
  const float* wq   = (const float*)d_in[1];
  const float* wk   = (const float*)d_in[2];
  const float* wv   = (const float*)d_in[3];
  const float* wo   = (const float*)d_in[4];
  const float* cosb = (const float*)d_in[7];
  const float* sinb = (const float*)d_in[8];
  const int*   sidx = (const int*)d_in[10];
  float* out = (float*)d_out;

  // workspace layout; wqb/wkb/wvb are contiguous so B_qkv = [wq;wk;wv]
  u16* ws  = (u16*)d_ws;
  u16* xb  = ws;                                  // 2048*4096
  u16* wqb = xb  + (size_t)S_LEN * DM;            // 4096*4096
  u16* wkb = wqb + (size_t)EQ * DM;               // 1024*4096
  u16* wvb = wkb + (size_t)EKV * DM;              // 1024*4096
  u16* wob = wvb + (size_t)EKV * DM;              // 4096*4096
  u16* qb  = wob + (size_t)DM * EQ;               // 2048*4096
  u16* kb  = qb  + (size_t)S_LEN * EQ;            // 2048*1024
  u16* vb  = kb  + (size_t)S_LEN * EKV;           // 2048*1024
  u16* vtb = vb  + (size_t)S_LEN * EKV;           // 1024*2048
  u16* aob = vtb + (size_t)S_LEN * EKV;           // 2048*4096

  cast_all<<<3072, 256, 0, stream>>>(x, wq, wk, wv, wo, xb, wqb, wkb, wvb, wob);
  // fused QKV projection: B = [wq;wk;wv] (6144 x 4096); 1D grid 512, XCD-swizzled
  gemm2p<3, true><<<512, 256, 0, stream>>>(xb, wqb, qb, kb, vb, DM);
  // fused k-RoPE + V-transpose (q-RoPE folded into attn): 1024 + 2048 blocks
  rope_tr<<<3072, 256, 0, stream>>>(kb, cosb, sinb, sidx, vb, vtb);
  attn_fwd<<<dim3(16, NH), 256, 0, stream>>>(qb, kb, vtb, aob, cosb, sinb, sidx);
  // O projection: 1D grid 512, XCD-swizzled
  gemm2p<2, false><<<512, 256, 0, stream>>>(aob, wob, out, nullptr, nullptr, EQ);
}